// Round 14
// baseline (59.648 us; speedup 1.0000x reference)
//
#include <hip/hip_runtime.h>
#include <hip/hip_bf16.h>

// Problem constants (from reference setup_inputs)
#define B_N    4096      // batch
#define D_K    1024      // feature dim
#define N_C    1024      // number of distinct ids (N_ID) = LUT rows used
#define MARGIN 0.3f

typedef __attribute__((ext_vector_type(8))) short short8;
typedef __attribute__((ext_vector_type(4))) float f32x4;

__device__ inline ushort f2bf(float f) {
    unsigned u = __float_as_uint(f);
    unsigned r = (u + 0x7fffu + ((u >> 16) & 1u)) >> 16;
    return (ushort)r;
}

__device__ inline void async16(const ushort* g, ushort* l) {
    __builtin_amdgcn_global_load_lds(
        (const __attribute__((address_space(1))) void*)g,
        (__attribute__((address_space(3))) void*)l,
        16, 0, 0);
}

// Fused prep:
//  blocks 0..4095: feat rows -> bf16 row-major + norms (first 16 also init
//  maxb/minb); blocks 4096..5119: lut rows 0..1023 -> bf16 + norms;
//  block 5120: id histogram via LDS.
__global__ void prep_all(const float* __restrict__ feat,
                         const float* __restrict__ lut,
                         const int* __restrict__ id,
                         ushort* __restrict__ featB, ushort* __restrict__ lutB,
                         float* __restrict__ sq_a, float* __restrict__ sq_b,
                         int* __restrict__ cnt,
                         int* __restrict__ maxb, int* __restrict__ minb) {
    int b = blockIdx.x;
    int t = threadIdx.x;                       // 256 threads

    if (b == B_N + N_C) {                      // histogram block
        __shared__ int hc[N_C];
        #pragma unroll
        for (int i = 0; i < 4; i++) hc[t * 4 + i] = 0;
        __syncthreads();
        #pragma unroll
        for (int i = 0; i < 16; i++) atomicAdd(&hc[id[t * 16 + i]], 1);
        __syncthreads();
        #pragma unroll
        for (int i = 0; i < 4; i++) cnt[t * 4 + i] = hc[t * 4 + i];
        return;
    }

    if (b < 16) {                              // 16*256 = 4096 entries
        int i = b * 256 + t;
        maxb[i] = 0;                           // 0.0f
        minb[i] = 0x7F800000;                  // +inf
    }
    const float* src; ushort* dst; float* sq;
    if (b < B_N) {
        src = feat + (size_t)b * D_K;
        dst = featB + (size_t)b * D_K;
        sq  = sq_a + b;
    } else {
        int c = b - B_N;                       // 0..1023
        src = lut + (size_t)c * D_K;
        dst = lutB + (size_t)c * D_K;
        sq  = sq_b + c;
    }
    float4 v = ((const float4*)src)[t];
    float ss = v.x * v.x + v.y * v.y + v.z * v.z + v.w * v.w;
    ushort4 bb;
    bb.x = f2bf(v.x); bb.y = f2bf(v.y); bb.z = f2bf(v.z); bb.w = f2bf(v.w);
    ((ushort4*)dst)[t] = bb;

    int lane = t & 63, w = t >> 6;
    #pragma unroll
    for (int o = 1; o < 64; o <<= 1) ss += __shfl_xor(ss, o);
    __shared__ float red[4];
    if (lane == 0) red[w] = ss;
    __syncthreads();
    if (t == 0) *sq = red[0] + red[1] + red[2] + red[3];
}

// 256x256-tile bf16 MFMA GEMM over D = feat x lut[0:1024]^T (M=4096,
// N=1024, K=1024) — R7's structure verbatim (best measured per-ktile cost,
// 1055 cyc/ktile): BK=32, TRIPLE-buffered LDS (96 KiB, 2-ktile staging
// lead), counted vmcnt(4) per tile, 2 paced phases/tile, zero-conflict
// row-pair XOR swizzle, setprio. Grid 64 blocks (1 per CU on 64 CUs) —
// big efficient blocks beat many floor-bound small ones (R9-R13 lesson).
// 8 waves 2(M)x4(N); per-wave 128x64 via 8x4 frags of 16x16x32.
__global__ __launch_bounds__(512, 2)
void dist_kernel(const ushort* __restrict__ A, const ushort* __restrict__ Bm,
                 const float* __restrict__ sqa, const float* __restrict__ sqb,
                 const int* __restrict__ ids, const int* __restrict__ cnt,
                 int* __restrict__ maxb, int* __restrict__ minb) {
    __shared__ ushort lds_[3 * 16384];   // 3 bufs x (A 8192 + B 8192) elems

    const int t = threadIdx.x;
    const int lane = t & 63;
    const int wid = t >> 6;          // 8 waves
    const int wr = wid >> 2;         // 0..1 (M)
    const int wc = wid & 3;          // 0..3 (N)
    const int l15 = lane & 15;
    const int h = lane >> 4;

    // T1 XCD swizzle: 64 blocks (64%8==0, bijective). XCD k owns row-tile
    // pairs {2k,2k+1} x all 4 col-tiles: A 1 MB + B 2 MB < 4 MB L2.
    const int bid = blockIdx.y * gridDim.x + blockIdx.x;   // gridDim.x = 4
    const int swz = (bid & 7) * 8 + (bid >> 3);
    const int rb = swz >> 2, cb = swz & 3;    // rb 0..15, cb 0..3

    // ---- staging sources: 2 instrs per operand per tile (512thr x 16B).
    // Linear phys elem p = q*4096 + t*8; line rp=p>>6, slot'=(p>>3)&7;
    // logical slot = slot' ^ (rp&7); r = rp*2 + (slot>>2); j = slot&3.
    const ushort* gsrc[2][2];        // [op A/B][q]
    #pragma unroll
    for (int q = 0; q < 2; q++) {
        int p = q * 4096 + t * 8;
        int rp = p >> 6;
        int sl = ((p >> 3) & 7) ^ (rp & 7);
        int r = rp * 2 + (sl >> 2);
        int j = sl & 3;
        gsrc[0][q] = A  + (size_t)(rb * 256 + r) * D_K + j * 8;
        gsrc[1][q] = Bm + (size_t)(cb * 256 + r) * D_K + j * 8;
    }
    const int lds_wo = wid * 512;    // wave-uniform lane-block offset (elems)

    // ---- swizzled fragment read offsets (elements within an 8192 buffer)
    int offA[8], offB[4];
    {
        int par = (l15 & 1) << 2;
        int a0 = (wr * 128 + l15) >> 1;
        #pragma unroll
        for (int mf = 0; mf < 8; mf++) {
            int line = a0 + mf * 8;
            offA[mf] = line * 64 + (((par | h) ^ (line & 7)) << 3);
        }
        int b0 = (wc * 64 + l15) >> 1;
        #pragma unroll
        for (int nf = 0; nf < 4; nf++) {
            int line = b0 + nf * 8;
            offB[nf] = line * 64 + (((par | h) ^ (line & 7)) << 3);
        }
    }

    f32x4 acc[8][4] = {};

    // ---- prologue: stage tiles 0 and 1 into bufs 0 and 1
    #pragma unroll
    for (int kt0 = 0; kt0 < 2; kt0++) {
        ushort* base = lds_ + kt0 * 16384;
        async16(gsrc[0][0] + kt0 * 32, base + lds_wo);
        async16(gsrc[0][1] + kt0 * 32, base + 4096 + lds_wo);
        async16(gsrc[1][0] + kt0 * 32, base + 8192 + lds_wo);
        async16(gsrc[1][1] + kt0 * 32, base + 12288 + lds_wo);
    }

    int s3 = 0, w3 = 2;
    for (int kt = 0; kt < 32; ++kt) {
        const ushort* sA = lds_ + s3 * 16384;
        const ushort* sB = sA + 8192;
        ushort* wA = lds_ + w3 * 16384;
        ushort* wB = wA + 8192;
        const int nc = (kt + 2) * 32;
        const bool more = (kt <= 29);

        // B1: tile kt resident (vmcnt: this wave's DMAs; barrier: all waves)
        if (kt < 31) asm volatile("s_waitcnt vmcnt(4)" ::: "memory");
        else         asm volatile("s_waitcnt vmcnt(0)" ::: "memory");
        __builtin_amdgcn_sched_barrier(0);
        __builtin_amdgcn_s_barrier();
        __builtin_amdgcn_sched_barrier(0);

        short8 afv[8], bfv[4];
        #pragma unroll
        for (int mf = 0; mf < 4; mf++)
            afv[mf] = *(const short8*)(sA + offA[mf]);
        #pragma unroll
        for (int nf = 0; nf < 4; nf++)
            bfv[nf] = *(const short8*)(sB + offB[nf]);
        if (more) {
            async16(gsrc[0][0] + nc, wA + lds_wo);
            async16(gsrc[0][1] + nc, wA + 4096 + lds_wo);
        }
        asm volatile("s_waitcnt lgkmcnt(0)" ::: "memory");
        __builtin_amdgcn_sched_barrier(0);
        __builtin_amdgcn_s_setprio(1);
        #pragma unroll
        for (int mf = 0; mf < 4; mf++)
            #pragma unroll
            for (int nf = 0; nf < 4; nf++)
                acc[mf][nf] = __builtin_amdgcn_mfma_f32_16x16x32_bf16(
                    afv[mf], bfv[nf], acc[mf][nf], 0, 0, 0);
        __builtin_amdgcn_s_setprio(0);

        // Q1 reads + B-stage in Q0's shadow (hidden under B2)
        #pragma unroll
        for (int mf = 4; mf < 8; mf++)
            afv[mf] = *(const short8*)(sA + offA[mf]);
        if (more) {
            async16(gsrc[1][0] + nc, wB + lds_wo);
            async16(gsrc[1][1] + nc, wB + 4096 + lds_wo);
        }
        __builtin_amdgcn_sched_barrier(0);
        __builtin_amdgcn_s_barrier();    // B2: phase pacing
        asm volatile("s_waitcnt lgkmcnt(0)" ::: "memory");
        __builtin_amdgcn_sched_barrier(0);
        __builtin_amdgcn_s_setprio(1);
        #pragma unroll
        for (int mf = 4; mf < 8; mf++)
            #pragma unroll
            for (int nf = 0; nf < 4; nf++)
                acc[mf][nf] = __builtin_amdgcn_mfma_f32_16x16x32_bf16(
                    afv[mf], bfv[nf], acc[mf][nf], 0, 0, 0);
        __builtin_amdgcn_s_setprio(0);
        __builtin_amdgcn_sched_barrier(0);

        s3 = (s3 == 2) ? 0 : s3 + 1;
        w3 = (w3 == 2) ? 0 : w3 + 1;
    }

    // Epilogue: col c IS the id. pos = (c==ida && cnt[c]>=2);
    // neg = (cnt[c]>0 && c!=ida). Per-row max/min over this block's 256 cols.
    int colg[4]; float sb2[4]; int c2[4];
    #pragma unroll
    for (int nf = 0; nf < 4; nf++) {
        int c = cb * 256 + wc * 64 + nf * 16 + l15;
        colg[nf] = c; sb2[nf] = sqb[c]; c2[nf] = cnt[c];
    }
    #pragma unroll
    for (int m = 0; m < 8; m++) {
        #pragma unroll
        for (int r = 0; r < 4; r++) {
            int row = rb * 256 + wr * 128 + m * 16 + h * 4 + r;
            float sa = sqa[row];
            int ida = ids[row];
            float mx = 0.0f, mn = 3.0e38f;
            #pragma unroll
            for (int nf = 0; nf < 4; nf++) {
                float s2 = sa + sb2[nf] - 2.0f * acc[m][nf][r];
                float d = sqrtf(fmaxf(s2, 0.0f) + 1e-12f);
                bool iseq = (colg[nf] == ida);
                float pv = (iseq && c2[nf] >= 2) ? d : 0.0f;
                float nv = (c2[nf] > 0 && !iseq) ? d : 3.0e38f;
                mx = fmaxf(mx, pv);
                mn = fminf(mn, nv);
            }
            #pragma unroll
            for (int o = 1; o < 16; o <<= 1) {
                mx = fmaxf(mx, __shfl_xor(mx, o));
                mn = fminf(mn, __shfl_xor(mn, o));
            }
            if (l15 == 0) {
                atomicMax(maxb + row, __float_as_int(mx));
                atomicMin(minb + row, __float_as_int(mn));
            }
        }
    }
}

__global__ void finalize_k(const int* __restrict__ maxb, const int* __restrict__ minb,
                           float* __restrict__ out) {
    int i = blockIdx.x * blockDim.x + threadIdx.x;
    if (i < B_N) {
        float z = __int_as_float(maxb[i]) - __int_as_float(minb[i]) + MARGIN;
        out[i] = fmaxf(z, 0.0f);
    }
}

extern "C" void kernel_launch(void* const* d_in, const int* in_sizes, int n_in,
                              void* d_out, int out_size, void* d_ws, size_t ws_size,
                              hipStream_t stream) {
    const float* feat = (const float*)d_in[0];
    const float* lut  = (const float*)d_in[1];
    const int*   id   = (const int*)d_in[2];
    float* out = (float*)d_out;

    // workspace layout
    char* ws = (char*)d_ws;
    ushort* featB = (ushort*)ws;                                   // 8 MiB
    ushort* lutB  = (ushort*)(ws + (size_t)B_N * D_K * 2);         // 2 MiB
    float*  sq_a  = (float*)(ws + (size_t)(B_N + N_C) * D_K * 2);
    float*  sq_b  = sq_a + B_N;
    int*    cnt   = (int*)(sq_b + N_C);
    int*    maxb  = cnt + N_C;
    int*    minb  = maxb + B_N;

    prep_all<<<B_N + N_C + 1, 256, 0, stream>>>(feat, lut, id, featB, lutB,
                                                sq_a, sq_b, cnt, maxb, minb);

    dim3 grid(N_C / 256, B_N / 256);   // 4 x 16 = 64 blocks
    dist_kernel<<<grid, 512, 0, stream>>>(featB, lutB, sq_a, sq_b, id, cnt,
                                          maxb, minb);

    finalize_k<<<16, 256, 0, stream>>>(maxb, minb, out);
}

// Round 15
// 34.444 us; speedup vs baseline: 1.7317x; 1.7317x over previous
//
#include <hip/hip_runtime.h>
#include <hip/hip_bf16.h>

// Problem constants (from reference setup_inputs)
#define B_N    4096      // batch
#define D_K    1024      // feature dim
#define N_C    1024      // number of distinct ids (N_ID) = LUT rows used
#define MARGIN 0.3f

typedef __attribute__((ext_vector_type(8))) short short8;
typedef __attribute__((ext_vector_type(4))) float f32x4;

__device__ inline ushort f2bf(float f) {
    unsigned u = __float_as_uint(f);
    unsigned r = (u + 0x7fffu + ((u >> 16) & 1u)) >> 16;
    return (ushort)r;
}

__device__ inline void async16(const ushort* g, ushort* l) {
    __builtin_amdgcn_global_load_lds(
        (const __attribute__((address_space(1))) void*)g,
        (__attribute__((address_space(3))) void*)l,
        16, 0, 0);
}

// Fused prep:
//  blocks 0..4095: feat rows -> bf16 row-major + norms (first 16 also init
//  maxb/minb); blocks 4096..5119: lut rows 0..1023 -> bf16 + norms;
//  block 5120: id histogram via LDS.
__global__ void prep_all(const float* __restrict__ feat,
                         const float* __restrict__ lut,
                         const int* __restrict__ id,
                         ushort* __restrict__ featB, ushort* __restrict__ lutB,
                         float* __restrict__ sq_a, float* __restrict__ sq_b,
                         int* __restrict__ cnt,
                         int* __restrict__ maxb, int* __restrict__ minb) {
    int b = blockIdx.x;
    int t = threadIdx.x;                       // 256 threads

    if (b == B_N + N_C) {                      // histogram block
        __shared__ int hc[N_C];
        #pragma unroll
        for (int i = 0; i < 4; i++) hc[t * 4 + i] = 0;
        __syncthreads();
        #pragma unroll
        for (int i = 0; i < 16; i++) atomicAdd(&hc[id[t * 16 + i]], 1);
        __syncthreads();
        #pragma unroll
        for (int i = 0; i < 4; i++) cnt[t * 4 + i] = hc[t * 4 + i];
        return;
    }

    if (b < 16) {                              // 16*256 = 4096 entries
        int i = b * 256 + t;
        maxb[i] = 0;                           // 0.0f
        minb[i] = 0x7F800000;                  // +inf
    }
    const float* src; ushort* dst; float* sq;
    if (b < B_N) {
        src = feat + (size_t)b * D_K;
        dst = featB + (size_t)b * D_K;
        sq  = sq_a + b;
    } else {
        int c = b - B_N;                       // 0..1023
        src = lut + (size_t)c * D_K;
        dst = lutB + (size_t)c * D_K;
        sq  = sq_b + c;
    }
    float4 v = ((const float4*)src)[t];
    float ss = v.x * v.x + v.y * v.y + v.z * v.z + v.w * v.w;
    ushort4 bb;
    bb.x = f2bf(v.x); bb.y = f2bf(v.y); bb.z = f2bf(v.z); bb.w = f2bf(v.w);
    ((ushort4*)dst)[t] = bb;

    int lane = t & 63, w = t >> 6;
    #pragma unroll
    for (int o = 1; o < 64; o <<= 1) ss += __shfl_xor(ss, o);
    __shared__ float red[4];
    if (lane == 0) red[w] = ss;
    __syncthreads();
    if (t == 0) *sq = red[0] + red[1] + red[2] + red[3];
}

// 64x64-tile bf16 MFMA GEMM over D = feat x lut[0:1024]^T (M=4096, N=1024,
// K=1024). R12's TLP regime (1024 blocks, 4 blocks/CU, 256 thr) with HALF
// the sync rounds: BK=64 -> 16 K-tiles, 8 MFMA + 8 ds_read per wave per
// round. LDS 32 KB (2 x 16 KB dbuf). Counted vmcnt(4) (4 staging calls per
// ktile in flight). Chunk-XOR swizzle for 128-B rows: c' = c ^ (r&7) ->
// exactly 8 words/bank per b128 read (conflict-free minimum).
__global__ __launch_bounds__(256, 4)
void dist_kernel(const ushort* __restrict__ A, const ushort* __restrict__ Bm,
                 const float* __restrict__ sqa, const float* __restrict__ sqb,
                 const int* __restrict__ ids, const int* __restrict__ cnt,
                 int* __restrict__ maxb, int* __restrict__ minb) {
    __shared__ ushort lds_[2 * 8192];   // 2 bufs x (A 4096 + B 4096 elems)

    const int t = threadIdx.x;
    const int lane = t & 63;
    const int wid = t >> 6;          // 4 waves: 2(M) x 2(N)
    const int wr = wid >> 1;
    const int wc = wid & 1;
    const int l15 = lane & 15;
    const int h = lane >> 4;
    const int wo = wid * 512;        // per-wave in-call LDS offset (elems)

    // T1 XCD swizzle: 1024 blocks -> XCD k owns row-bands 8k..8k+7 x all 16
    // col-tiles (A-band 512 rows = 1 MB + B 2 MB < 4 MB L2).
    const int bid = blockIdx.y * gridDim.x + blockIdx.x;   // gridDim.x = 16
    const int swz = (bid & 7) * 128 + (bid >> 3);
    const int rb = swz >> 4, cb = swz & 15;    // rb 0..63, cb 0..15

    // ---- staging sources: 2 calls per operand per ktile (each 256thr x 16B
    // = 2048 elems = 32 rows of 64). Phys elem p = q*2048 + t*8;
    // row r = p>>6; chunk j = (p>>3)&7; source chunk = j ^ (r&7).
    const ushort* gA[2]; const ushort* gB[2];
    #pragma unroll
    for (int q = 0; q < 2; q++) {
        int p = q * 2048 + t * 8;
        int r = p >> 6;
        int j = (p >> 3) & 7;
        int col = (j ^ (r & 7)) << 3;
        gA[q] = A  + (size_t)(rb * 64 + r) * D_K + col;
        gB[q] = Bm + (size_t)(cb * 64 + r) * D_K + col;
    }

    // ---- swizzled fragment read offsets (elements within a 4096 buffer).
    // Logical chunk for (ks, h) = ks*4 + h; row = base + l15;
    // phys chunk = (ks*4+h) ^ (l15&7)  (16/32-row strides are 0 mod 8).
    const int q7 = l15 & 7;
    int offA[2][2], offB[2][2];
    #pragma unroll
    for (int mf = 0; mf < 2; mf++)
        #pragma unroll
        for (int ks = 0; ks < 2; ks++) {
            offA[mf][ks] = (wr * 32 + mf * 16 + l15) * 64
                         + (((ks * 4 + h) ^ q7) << 3);
            offB[mf][ks] = (wc * 32 + mf * 16 + l15) * 64
                         + (((ks * 4 + h) ^ q7) << 3);
        }

    f32x4 acc[2][2] = {};

    // ---- prologue: stage tile 0 into buf 0 (A: q0,q1; B: q0,q1)
    async16(gA[0], lds_ + wo);
    async16(gA[1], lds_ + 2048 + wo);
    async16(gB[0], lds_ + 4096 + wo);
    async16(gB[1], lds_ + 4096 + 2048 + wo);

    for (int kt = 0; kt < 16; ++kt) {
        const int s = kt & 1;
        const ushort* sA = lds_ + s * 8192;
        const ushort* sB = sA + 4096;

        if (kt < 15) {       // stage kt+1 into other buf (reads done at kt-1)
            ushort* wb = lds_ + (s ^ 1) * 8192;
            const int nc = (kt + 1) * 64;
            async16(gA[0] + nc, wb + wo);
            async16(gA[1] + nc, wb + 2048 + wo);
            async16(gB[0] + nc, wb + 4096 + wo);
            async16(gB[1] + nc, wb + 4096 + 2048 + wo);
            asm volatile("s_waitcnt vmcnt(4)" ::: "memory");  // kt landed
        } else {
            asm volatile("s_waitcnt vmcnt(0)" ::: "memory");
        }
        __builtin_amdgcn_sched_barrier(0);
        __builtin_amdgcn_s_barrier();        // RAW: tile kt visible
        __builtin_amdgcn_sched_barrier(0);

        short8 afv[2][2], bfv[2][2];
        #pragma unroll
        for (int mf = 0; mf < 2; mf++)
            #pragma unroll
            for (int ks = 0; ks < 2; ks++) {
                afv[mf][ks] = *(const short8*)(sA + offA[mf][ks]);
                bfv[mf][ks] = *(const short8*)(sB + offB[mf][ks]);
            }
        asm volatile("s_waitcnt lgkmcnt(0)" ::: "memory");
        __builtin_amdgcn_sched_barrier(0);
        __builtin_amdgcn_s_setprio(1);
        #pragma unroll
        for (int mf = 0; mf < 2; mf++)
            #pragma unroll
            for (int nf = 0; nf < 2; nf++)
                #pragma unroll
                for (int ks = 0; ks < 2; ks++)
                    acc[mf][nf] = __builtin_amdgcn_mfma_f32_16x16x32_bf16(
                        afv[mf][ks], bfv[nf][ks], acc[mf][nf], 0, 0, 0);
        __builtin_amdgcn_s_setprio(0);
        __builtin_amdgcn_sched_barrier(0);
        __builtin_amdgcn_s_barrier();        // WAR: reads done before overwrite
    }

    // Epilogue: col c IS the id. pos = (c==ida && cnt[c]>=2);
    // neg = (cnt[c]>0 && c!=ida). Per-row max/min over this block's 64 cols.
    int colg[2]; float sb2[2]; int c2[2];
    #pragma unroll
    for (int nf = 0; nf < 2; nf++) {
        int c = cb * 64 + wc * 32 + nf * 16 + l15;
        colg[nf] = c; sb2[nf] = sqb[c]; c2[nf] = cnt[c];
    }
    #pragma unroll
    for (int m = 0; m < 2; m++) {
        #pragma unroll
        for (int r = 0; r < 4; r++) {
            int row = rb * 64 + wr * 32 + m * 16 + h * 4 + r;
            float sa = sqa[row];
            int ida = ids[row];
            float mx = 0.0f, mn = 3.0e38f;
            #pragma unroll
            for (int nf = 0; nf < 2; nf++) {
                float s2 = sa + sb2[nf] - 2.0f * acc[m][nf][r];
                float d = sqrtf(fmaxf(s2, 0.0f) + 1e-12f);
                bool iseq = (colg[nf] == ida);
                float pv = (iseq && c2[nf] >= 2) ? d : 0.0f;
                float nv = (c2[nf] > 0 && !iseq) ? d : 3.0e38f;
                mx = fmaxf(mx, pv);
                mn = fminf(mn, nv);
            }
            #pragma unroll
            for (int o = 1; o < 16; o <<= 1) {
                mx = fmaxf(mx, __shfl_xor(mx, o));
                mn = fminf(mn, __shfl_xor(mn, o));
            }
            if (l15 == 0) {
                atomicMax(maxb + row, __float_as_int(mx));
                atomicMin(minb + row, __float_as_int(mn));
            }
        }
    }
}

__global__ void finalize_k(const int* __restrict__ maxb, const int* __restrict__ minb,
                           float* __restrict__ out) {
    int i = blockIdx.x * blockDim.x + threadIdx.x;
    if (i < B_N) {
        float z = __int_as_float(maxb[i]) - __int_as_float(minb[i]) + MARGIN;
        out[i] = fmaxf(z, 0.0f);
    }
}

extern "C" void kernel_launch(void* const* d_in, const int* in_sizes, int n_in,
                              void* d_out, int out_size, void* d_ws, size_t ws_size,
                              hipStream_t stream) {
    const float* feat = (const float*)d_in[0];
    const float* lut  = (const float*)d_in[1];
    const int*   id   = (const int*)d_in[2];
    float* out = (float*)d_out;

    // workspace layout
    char* ws = (char*)d_ws;
    ushort* featB = (ushort*)ws;                                   // 8 MiB
    ushort* lutB  = (ushort*)(ws + (size_t)B_N * D_K * 2);         // 2 MiB
    float*  sq_a  = (float*)(ws + (size_t)(B_N + N_C) * D_K * 2);
    float*  sq_b  = sq_a + B_N;
    int*    cnt   = (int*)(sq_b + N_C);
    int*    maxb  = cnt + N_C;
    int*    minb  = maxb + B_N;

    prep_all<<<B_N + N_C + 1, 256, 0, stream>>>(feat, lut, id, featB, lutB,
                                                sq_a, sq_b, cnt, maxb, minb);

    dim3 grid(N_C / 64, B_N / 64);     // 16 x 64 = 1024 blocks
    dist_kernel<<<grid, 256, 0, stream>>>(featB, lutB, sq_a, sq_b, id, cnt,
                                          maxb, minb);

    finalize_k<<<16, 256, 0, stream>>>(maxb, minb, out);
}

// Round 16
// 34.101 us; speedup vs baseline: 1.7492x; 1.0101x over previous
//
#include <hip/hip_runtime.h>
#include <hip/hip_bf16.h>

// Problem constants (from reference setup_inputs)
#define B_N    4096      // batch
#define D_K    1024      // feature dim
#define N_C    1024      // number of distinct ids (N_ID) = LUT rows used
#define MARGIN 0.3f

typedef __attribute__((ext_vector_type(8))) short short8;
typedef __attribute__((ext_vector_type(4))) float f32x4;

__device__ inline ushort f2bf(float f) {
    unsigned u = __float_as_uint(f);
    unsigned r = (u + 0x7fffu + ((u >> 16) & 1u)) >> 16;
    return (ushort)r;
}

__device__ inline void async16(const ushort* g, ushort* l) {
    __builtin_amdgcn_global_load_lds(
        (const __attribute__((address_space(1))) void*)g,
        (__attribute__((address_space(3))) void*)l,
        16, 0, 0);
}

// Fused prep:
//  blocks 0..4095: feat rows -> bf16 row-major + norms (first 16 also init
//  maxb/minb); blocks 4096..5119: lut rows 0..1023 -> bf16 + norms;
//  block 5120: id histogram via LDS.
__global__ void prep_all(const float* __restrict__ feat,
                         const float* __restrict__ lut,
                         const int* __restrict__ id,
                         ushort* __restrict__ featB, ushort* __restrict__ lutB,
                         float* __restrict__ sq_a, float* __restrict__ sq_b,
                         int* __restrict__ cnt,
                         int* __restrict__ maxb, int* __restrict__ minb) {
    int b = blockIdx.x;
    int t = threadIdx.x;                       // 256 threads

    if (b == B_N + N_C) {                      // histogram block
        __shared__ int hc[N_C];
        #pragma unroll
        for (int i = 0; i < 4; i++) hc[t * 4 + i] = 0;
        __syncthreads();
        #pragma unroll
        for (int i = 0; i < 16; i++) atomicAdd(&hc[id[t * 16 + i]], 1);
        __syncthreads();
        #pragma unroll
        for (int i = 0; i < 4; i++) cnt[t * 4 + i] = hc[t * 4 + i];
        return;
    }

    if (b < 16) {                              // 16*256 = 4096 entries
        int i = b * 256 + t;
        maxb[i] = 0;                           // 0.0f
        minb[i] = 0x7F800000;                  // +inf
    }
    const float* src; ushort* dst; float* sq;
    if (b < B_N) {
        src = feat + (size_t)b * D_K;
        dst = featB + (size_t)b * D_K;
        sq  = sq_a + b;
    } else {
        int c = b - B_N;                       // 0..1023
        src = lut + (size_t)c * D_K;
        dst = lutB + (size_t)c * D_K;
        sq  = sq_b + c;
    }
    float4 v = ((const float4*)src)[t];
    float ss = v.x * v.x + v.y * v.y + v.z * v.z + v.w * v.w;
    ushort4 bb;
    bb.x = f2bf(v.x); bb.y = f2bf(v.y); bb.z = f2bf(v.z); bb.w = f2bf(v.w);
    ((ushort4*)dst)[t] = bb;

    int lane = t & 63, w = t >> 6;
    #pragma unroll
    for (int o = 1; o < 64; o <<= 1) ss += __shfl_xor(ss, o);
    __shared__ float red[4];
    if (lane == 0) red[w] = ss;
    __syncthreads();
    if (t == 0) *sq = red[0] + red[1] + red[2] + red[3];
}

// 128x64-tile bf16 MFMA GEMM over D = feat x lut[0:1024]^T (M=4096, N=1024,
// K=1024). Sync-rounds-per-CU halved again vs R15 (confirmed lever):
// grid 512 blocks = 2/CU (TLP=2), BK=64 -> 16 K-tiles/block = 32 rounds/CU.
// Per round: 16 MFMA + 12 ds_read_b128 per wave. LDS 48 KB (2 x 24 KB dbuf).
// Counted vmcnt(6) (6 staging calls per ktile). Chunk-XOR swizzle
// (c' = c ^ (r&7)), conflict-free (verified 0 in R4/R7/R8/R10/R12).
// 4 waves 2(M)x2(N); per-wave 64x32 via 4x2 frags of 16x16x32.
__global__ __launch_bounds__(256, 2)
void dist_kernel(const ushort* __restrict__ A, const ushort* __restrict__ Bm,
                 const float* __restrict__ sqa, const float* __restrict__ sqb,
                 const int* __restrict__ ids, const int* __restrict__ cnt,
                 int* __restrict__ maxb, int* __restrict__ minb) {
    __shared__ ushort lds_[2 * 12288];  // 2 bufs x (A 8192 + B 4096 elems)

    const int t = threadIdx.x;
    const int lane = t & 63;
    const int wid = t >> 6;          // 4 waves: 2(M) x 2(N)
    const int wr = wid >> 1;
    const int wc = wid & 1;
    const int l15 = lane & 15;
    const int h = lane >> 4;
    const int wo = wid * 512;        // per-wave in-call LDS offset (elems)

    // T1 XCD swizzle: 512 blocks (512%8==0, bijective). XCD k owns
    // rb k*4..k*4+3 (512 rows = 1 MB) x all 16 col-tiles (B 2 MB) < 4 MB L2.
    const int bid = blockIdx.y * gridDim.x + blockIdx.x;   // gridDim.x = 16
    const int swz = (bid & 7) * 64 + (bid >> 3);
    const int rb = swz >> 4, cb = swz & 15;    // rb 0..31, cb 0..15

    // ---- staging sources. A: 4 calls (q=0..3), B: 2 calls (q=0..1); each
    // 256thr x 16B = 2048 elems = 32 rows of 64. Phys elem p = q*2048 + t*8;
    // row r = p>>6; chunk j = (p>>3)&7; source chunk = j ^ (r&7).
    const ushort* gA[4]; const ushort* gB[2];
    #pragma unroll
    for (int q = 0; q < 4; q++) {
        int p = q * 2048 + t * 8;
        int r = p >> 6;
        int j = (p >> 3) & 7;
        int col = (j ^ (r & 7)) << 3;
        gA[q] = A + (size_t)(rb * 128 + r) * D_K + col;
        if (q < 2)
            gB[q] = Bm + (size_t)(cb * 64 + r) * D_K + col;
    }

    // ---- swizzled fragment read offsets. Row strides (64, 32, 16) are all
    // 0 mod 8, so r&7 = l15&7 for every fragment row.
    const int q7 = l15 & 7;
    int offA[4][2], offB[2][2];
    #pragma unroll
    for (int ks = 0; ks < 2; ks++) {
        int xc = ((ks * 4 + h) ^ q7) << 3;
        #pragma unroll
        for (int mf = 0; mf < 4; mf++)
            offA[mf][ks] = (wr * 64 + mf * 16 + l15) * 64 + xc;
        #pragma unroll
        for (int nf = 0; nf < 2; nf++)
            offB[nf][ks] = (wc * 32 + nf * 16 + l15) * 64 + xc;
    }

    f32x4 acc[4][2] = {};

    // ---- prologue: stage tile 0 into buf 0 (A q0..q3, B q0..q1)
    #pragma unroll
    for (int q = 0; q < 4; q++) async16(gA[q], lds_ + q * 2048 + wo);
    #pragma unroll
    for (int q = 0; q < 2; q++) async16(gB[q], lds_ + 8192 + q * 2048 + wo);

    for (int kt = 0; kt < 16; ++kt) {
        const int s = kt & 1;
        const ushort* sA = lds_ + s * 12288;
        const ushort* sB = sA + 8192;

        if (kt < 15) {       // stage kt+1 into other buf (reads done at kt-1)
            ushort* wb = lds_ + (s ^ 1) * 12288;
            const int nc = (kt + 1) * 64;
            #pragma unroll
            for (int q = 0; q < 4; q++)
                async16(gA[q] + nc, wb + q * 2048 + wo);
            #pragma unroll
            for (int q = 0; q < 2; q++)
                async16(gB[q] + nc, wb + 8192 + q * 2048 + wo);
            asm volatile("s_waitcnt vmcnt(6)" ::: "memory");  // kt landed
        } else {
            asm volatile("s_waitcnt vmcnt(0)" ::: "memory");
        }
        __builtin_amdgcn_sched_barrier(0);
        __builtin_amdgcn_s_barrier();        // RAW: tile kt visible
        __builtin_amdgcn_sched_barrier(0);

        short8 afv[4][2], bfv[2][2];
        #pragma unroll
        for (int mf = 0; mf < 4; mf++)
            #pragma unroll
            for (int ks = 0; ks < 2; ks++)
                afv[mf][ks] = *(const short8*)(sA + offA[mf][ks]);
        #pragma unroll
        for (int nf = 0; nf < 2; nf++)
            #pragma unroll
            for (int ks = 0; ks < 2; ks++)
                bfv[nf][ks] = *(const short8*)(sB + offB[nf][ks]);
        asm volatile("s_waitcnt lgkmcnt(0)" ::: "memory");
        __builtin_amdgcn_sched_barrier(0);
        __builtin_amdgcn_s_setprio(1);
        #pragma unroll
        for (int mf = 0; mf < 4; mf++)
            #pragma unroll
            for (int nf = 0; nf < 2; nf++)
                #pragma unroll
                for (int ks = 0; ks < 2; ks++)
                    acc[mf][nf] = __builtin_amdgcn_mfma_f32_16x16x32_bf16(
                        afv[mf][ks], bfv[nf][ks], acc[mf][nf], 0, 0, 0);
        __builtin_amdgcn_s_setprio(0);
        __builtin_amdgcn_sched_barrier(0);
        __builtin_amdgcn_s_barrier();        // WAR: reads done before overwrite
    }

    // Epilogue: col c IS the id. pos = (c==ida && cnt[c]>=2);
    // neg = (cnt[c]>0 && c!=ida). Per-row max/min over this block's 64 cols.
    int colg[2]; float sb2[2]; int c2[2];
    #pragma unroll
    for (int nf = 0; nf < 2; nf++) {
        int c = cb * 64 + wc * 32 + nf * 16 + l15;
        colg[nf] = c; sb2[nf] = sqb[c]; c2[nf] = cnt[c];
    }
    #pragma unroll
    for (int m = 0; m < 4; m++) {
        #pragma unroll
        for (int r = 0; r < 4; r++) {
            int row = rb * 128 + wr * 64 + m * 16 + h * 4 + r;
            float sa = sqa[row];
            int ida = ids[row];
            float mx = 0.0f, mn = 3.0e38f;
            #pragma unroll
            for (int nf = 0; nf < 2; nf++) {
                float s2 = sa + sb2[nf] - 2.0f * acc[m][nf][r];
                float d = sqrtf(fmaxf(s2, 0.0f) + 1e-12f);
                bool iseq = (colg[nf] == ida);
                float pv = (iseq && c2[nf] >= 2) ? d : 0.0f;
                float nv = (c2[nf] > 0 && !iseq) ? d : 3.0e38f;
                mx = fmaxf(mx, pv);
                mn = fminf(mn, nv);
            }
            #pragma unroll
            for (int o = 1; o < 16; o <<= 1) {
                mx = fmaxf(mx, __shfl_xor(mx, o));
                mn = fminf(mn, __shfl_xor(mn, o));
            }
            if (l15 == 0) {
                atomicMax(maxb + row, __float_as_int(mx));
                atomicMin(minb + row, __float_as_int(mn));
            }
        }
    }
}

__global__ void finalize_k(const int* __restrict__ maxb, const int* __restrict__ minb,
                           float* __restrict__ out) {
    int i = blockIdx.x * blockDim.x + threadIdx.x;
    if (i < B_N) {
        float z = __int_as_float(maxb[i]) - __int_as_float(minb[i]) + MARGIN;
        out[i] = fmaxf(z, 0.0f);
    }
}

extern "C" void kernel_launch(void* const* d_in, const int* in_sizes, int n_in,
                              void* d_out, int out_size, void* d_ws, size_t ws_size,
                              hipStream_t stream) {
    const float* feat = (const float*)d_in[0];
    const float* lut  = (const float*)d_in[1];
    const int*   id   = (const int*)d_in[2];
    float* out = (float*)d_out;

    // workspace layout
    char* ws = (char*)d_ws;
    ushort* featB = (ushort*)ws;                                   // 8 MiB
    ushort* lutB  = (ushort*)(ws + (size_t)B_N * D_K * 2);         // 2 MiB
    float*  sq_a  = (float*)(ws + (size_t)(B_N + N_C) * D_K * 2);
    float*  sq_b  = sq_a + B_N;
    int*    cnt   = (int*)(sq_b + N_C);
    int*    maxb  = cnt + N_C;
    int*    minb  = maxb + B_N;

    prep_all<<<B_N + N_C + 1, 256, 0, stream>>>(feat, lut, id, featB, lutB,
                                                sq_a, sq_b, cnt, maxb, minb);

    dim3 grid(N_C / 64, B_N / 128);    // 16 x 32 = 512 blocks
    dist_kernel<<<grid, 256, 0, stream>>>(featB, lutB, sq_a, sq_b, id, cnt,
                                          maxb, minb);

    finalize_k<<<16, 256, 0, stream>>>(maxb, minb, out);
}